// Round 3
// baseline (1305.048 us; speedup 1.0000x reference)
//
#include <hip/hip_runtime.h>
#include <hip/hip_cooperative_groups.h>

namespace cg = cooperative_groups;

// ConvTP: e3nn-style tensor product message passing + segment sum.
// N_NODES=50000, N_EDGES=800000, MUL=32
// R1: atomic storm (2.32ms). R2: CSR build + wave-per-node gather (903us).
// R3: block-scan (807us). R4: pipelined gather (797us, NULL -> latency theory dead).
// R5 (this): kill the scan chain via fixed-cap buckets (cap<=2048 slots/node in ws,
// spill list for robustness) and fuse scatter->gather->spill into ONE cooperative
// kernel (2 grid syncs). Removes hist+3 scan kernels + 5 launch gaps, and makes
// our work visible in rocprof top-5 (it was hidden under 318us poison fills).

#define IN_DIM 128
#define W_DIM 160
#define OUT_DIM 224
#define SPILL_CAP 4096

typedef float vf4 __attribute__((ext_vector_type(4)));

#define INV_SQRT3f 0.5773502691896258f
#define INV_SQRT2f 0.7071067811865476f

// ---------------- device phases (shared by fused + fallback) ----------------

__device__ __forceinline__ void scatter_phase(
    const int* __restrict__ eidx, int* __restrict__ cursor,
    int* __restrict__ spill_cnt, int4* __restrict__ spill,
    int2* __restrict__ buckets, int cap, int n_edges, int tid, int nthreads)
{
    int n_half = (n_edges + 1) >> 1;
    for (int t = tid; t < n_half; t += nthreads) {
        int e0 = 2 * t;
        if (e0 + 1 < n_edges) {
            int4 q = *(const int4*)(eidx + 4 * (size_t)t);   // (src0,dst0,src1,dst1)
            int p0 = atomicAdd(cursor + q.y, 1);
            if (p0 < cap) buckets[(size_t)q.y * cap + p0] = make_int2(e0, q.x);
            else { int sp = atomicAdd(spill_cnt, 1); if (sp < SPILL_CAP) spill[sp] = make_int4(e0, q.x, q.y, 0); }
            int p1 = atomicAdd(cursor + q.w, 1);
            if (p1 < cap) buckets[(size_t)q.w * cap + p1] = make_int2(e0 + 1, q.z);
            else { int sp = atomicAdd(spill_cnt, 1); if (sp < SPILL_CAP) spill[sp] = make_int4(e0 + 1, q.z, q.w, 0); }
        } else {
            int src = eidx[2 * e0];
            int dst = eidx[2 * e0 + 1];
            int p = atomicAdd(cursor + dst, 1);
            if (p < cap) buckets[(size_t)dst * cap + p] = make_int2(e0, src);
            else { int sp = atomicAdd(spill_cnt, 1); if (sp < SPILL_CAP) spill[sp] = make_int4(e0, src, dst, 0); }
        }
    }
}

__device__ __forceinline__ void gather_phase(
    const float* __restrict__ nf, const float* __restrict__ ang,
    const float* __restrict__ w, const int* __restrict__ cursor,
    const int2* __restrict__ buckets, int cap, float* __restrict__ out,
    int n_nodes, int wave_id, int n_waves, int lane)
{
    int c    = lane & 31;          // channel
    int half = lane >> 5;          // two contiguous edge sub-ranges per wave

    for (int node = wave_id; node < n_nodes; node += n_waves) {
        int cnt = cursor[node];
        if (cnt > cap) cnt = cap;                  // overflow edges handled by spill phase
        const int2* bp = buckets + (size_t)node * cap;
        int mid = (cnt + 1) >> 1;
        int lo = half ? mid : 0;
        int hi = half ? cnt : mid;

        float a0 = 0.f, a1 = 0.f, a2 = 0.f, a3 = 0.f, a4 = 0.f, a5 = 0.f, a6 = 0.f;

        for (int i = lo; i < hi; ++i) {
            int2 p = bp[i];
            int e = p.x, s = p.y;
            vf4 y = __builtin_nontemporal_load((const vf4*)(ang + 4 * (size_t)e));
            const float* hp = nf + (size_t)s * IN_DIM + c;
            float h0 = hp[0];
            float ha = hp[32];
            float hb = hp[64];
            float hc = hp[96];
            const float* wp = w + (size_t)e * W_DIM + c;
            float w0 = __builtin_nontemporal_load(wp);
            float w1 = __builtin_nontemporal_load(wp + 32);
            float w2 = __builtin_nontemporal_load(wp + 64);
            float w3 = __builtin_nontemporal_load(wp + 96);
            float w4 = __builtin_nontemporal_load(wp + 128);

            float dot = ha * y[1] + hb * y[2] + hc * y[3];
            a0 += w0 * h0 * y[0] + w3 * (INV_SQRT3f * dot);
            a1 += w1 * h0 * y[1] + w2 * ha * y[0];
            a2 += w1 * h0 * y[2] + w2 * hb * y[0];
            a3 += w1 * h0 * y[3] + w2 * hc * y[0];
            float w4s = w4 * INV_SQRT2f;
            a4 += w4s * (hb * y[3] - hc * y[2]);
            a5 += w4s * (hc * y[1] - ha * y[3]);
            a6 += w4s * (ha * y[2] - hb * y[1]);
        }

        // combine the two half-wave edge streams
        a0 += __shfl_xor(a0, 32);
        a1 += __shfl_xor(a1, 32);
        a2 += __shfl_xor(a2, 32);
        a3 += __shfl_xor(a3, 32);
        a4 += __shfl_xor(a4, 32);
        a5 += __shfl_xor(a5, 32);
        a6 += __shfl_xor(a6, 32);

        if (half == 0) {
            float* op = out + (size_t)node * OUT_DIM + c;
            __builtin_nontemporal_store(a0, op);
            __builtin_nontemporal_store(a1, op + 32);
            __builtin_nontemporal_store(a2, op + 64);
            __builtin_nontemporal_store(a3, op + 96);
            __builtin_nontemporal_store(a4, op + 128);
            __builtin_nontemporal_store(a5, op + 160);
            __builtin_nontemporal_store(a6, op + 192);
        }
    }
}

__device__ __forceinline__ void spill_phase(
    const float* __restrict__ nf, const float* __restrict__ ang,
    const float* __restrict__ w, const int4* __restrict__ spill,
    int n_spill, float* __restrict__ out, int tid, int nthreads)
{
    // expected n_spill == 0; correctness-only path (atomicAdd on top of stored out)
    for (int i = tid; i < n_spill; i += nthreads) {
        int4 s4 = spill[i];
        int e = s4.x, s = s4.y, dst = s4.z;
        vf4 y = *(const vf4*)(ang + 4 * (size_t)e);
        for (int c = 0; c < 32; ++c) {
            float h0 = nf[(size_t)s * IN_DIM + c];
            float ha = nf[(size_t)s * IN_DIM + 32 + c];
            float hb = nf[(size_t)s * IN_DIM + 64 + c];
            float hc = nf[(size_t)s * IN_DIM + 96 + c];
            const float* wp = w + (size_t)e * W_DIM + c;
            float w0 = wp[0], w1 = wp[32], w2 = wp[64], w3 = wp[96], w4 = wp[128];
            float* op = out + (size_t)dst * OUT_DIM + c;
            float dot = ha * y[1] + hb * y[2] + hc * y[3];
            atomicAdd(op,       w0 * h0 * y[0] + w3 * (INV_SQRT3f * dot));
            atomicAdd(op + 32,  w1 * h0 * y[1] + w2 * ha * y[0]);
            atomicAdd(op + 64,  w1 * h0 * y[2] + w2 * hb * y[0]);
            atomicAdd(op + 96,  w1 * h0 * y[3] + w2 * hc * y[0]);
            float w4s = w4 * INV_SQRT2f;
            atomicAdd(op + 128, w4s * (hb * y[3] - hc * y[2]));
            atomicAdd(op + 160, w4s * (hc * y[1] - ha * y[3]));
            atomicAdd(op + 192, w4s * (ha * y[2] - hb * y[1]));
        }
    }
}

// ---------------- fused cooperative kernel ----------------

__global__ void __launch_bounds__(256, 4) fused_conv(
    const float* __restrict__ nf, const float* __restrict__ ang,
    const int* __restrict__ eidx, const float* __restrict__ w,
    int* __restrict__ cursor, int* __restrict__ spill_cnt,
    int4* __restrict__ spill, int2* __restrict__ buckets,
    float* __restrict__ out, int n_edges, int n_nodes, int cap)
{
    cg::grid_group grid = cg::this_grid();
    int tid = blockIdx.x * blockDim.x + threadIdx.x;
    int nthreads = gridDim.x * blockDim.x;

    scatter_phase(eidx, cursor, spill_cnt, spill, buckets, cap, n_edges, tid, nthreads);

    __threadfence();
    grid.sync();

    int lane = threadIdx.x & 63;
    int wave_id = tid >> 6;
    int n_waves = nthreads >> 6;
    gather_phase(nf, ang, w, cursor, buckets, cap, out, n_nodes, wave_id, n_waves, lane);

    __threadfence();
    grid.sync();

    int n_spill = *spill_cnt;
    if (n_spill > SPILL_CAP) n_spill = SPILL_CAP;
    spill_phase(nf, ang, w, spill, n_spill, out, tid, nthreads);
}

// ---------------- non-cooperative fallbacks ----------------

__global__ void __launch_bounds__(256) scatter_k(
    const int* __restrict__ eidx, int* __restrict__ cursor,
    int* __restrict__ spill_cnt, int4* __restrict__ spill,
    int2* __restrict__ buckets, int cap, int n_edges)
{
    int tid = blockIdx.x * blockDim.x + threadIdx.x;
    scatter_phase(eidx, cursor, spill_cnt, spill, buckets, cap, n_edges,
                  tid, gridDim.x * blockDim.x);
}

__global__ void __launch_bounds__(256) gather_k(
    const float* __restrict__ nf, const float* __restrict__ ang,
    const float* __restrict__ w, const int* __restrict__ cursor,
    const int2* __restrict__ buckets, int cap, float* __restrict__ out, int n_nodes)
{
    int tid = blockIdx.x * blockDim.x + threadIdx.x;
    gather_phase(nf, ang, w, cursor, buckets, cap, out, n_nodes,
                 tid >> 6, (gridDim.x * blockDim.x) >> 6, threadIdx.x & 63);
}

__global__ void __launch_bounds__(256) spill_k(
    const float* __restrict__ nf, const float* __restrict__ ang,
    const float* __restrict__ w, const int* __restrict__ spill_cnt,
    const int4* __restrict__ spill, float* __restrict__ out)
{
    int n_spill = *spill_cnt;
    if (n_spill > SPILL_CAP) n_spill = SPILL_CAP;
    spill_phase(nf, ang, w, spill, n_spill, out,
                blockIdx.x * blockDim.x + threadIdx.x, gridDim.x * blockDim.x);
}

// ---------------- tiny-ws fallback (R1 atomic path) ----------------

__device__ __forceinline__ float elem(const float4& v, int i) {
    return ((const float*)&v)[i];
}

__global__ void __launch_bounds__(256) conv_tp_edges_atomic(
    const float* __restrict__ nf, const float* __restrict__ ang,
    const int* __restrict__ eidx, const float* __restrict__ w,
    float* __restrict__ out, int n_edges)
{
    int tid = blockIdx.x * blockDim.x + threadIdx.x;
    int e = tid >> 3;
    int t = tid & 7;
    if (e >= n_edges) return;

    int src = eidx[2 * e];
    int dst = eidx[2 * e + 1];
    float4 y = *(const float4*)(ang + 4 * (size_t)e);

    const float* hp = nf + (size_t)src * IN_DIM + 4 * t;
    float4 h0  = *(const float4*)(hp);
    float4 h1a = *(const float4*)(hp + 32);
    float4 h1b = *(const float4*)(hp + 64);
    float4 h1c = *(const float4*)(hp + 96);

    const float* wp = w + (size_t)e * W_DIM + 4 * t;
    float4 w0 = *(const float4*)(wp);
    float4 w1 = *(const float4*)(wp + 32);
    float4 w2 = *(const float4*)(wp + 64);
    float4 w3 = *(const float4*)(wp + 96);
    float4 w4 = *(const float4*)(wp + 128);

    float* op = out + (size_t)dst * OUT_DIM + 4 * t;

    #pragma unroll
    for (int i = 0; i < 4; ++i) {
        float h0c = elem(h0, i), ha = elem(h1a, i), hb = elem(h1b, i), hc = elem(h1c, i);
        float dot = ha * y.y + hb * y.z + hc * y.w;
        atomicAdd(op + i, elem(w0, i) * h0c * y.x + elem(w3, i) * (INV_SQRT3f * dot));
        float w1c = elem(w1, i), w2c = elem(w2, i);
        atomicAdd(op + 32 + i, w1c * h0c * y.y + w2c * ha * y.x);
        atomicAdd(op + 64 + i, w1c * h0c * y.z + w2c * hb * y.x);
        atomicAdd(op + 96 + i, w1c * h0c * y.w + w2c * hc * y.x);
        float w4c = elem(w4, i) * INV_SQRT2f;
        atomicAdd(op + 128 + i, w4c * (hb * y.w - hc * y.z));
        atomicAdd(op + 160 + i, w4c * (hc * y.y - ha * y.w));
        atomicAdd(op + 192 + i, w4c * (ha * y.z - hb * y.y));
    }
}

// ---------------- host launcher ----------------

extern "C" void kernel_launch(void* const* d_in, const int* in_sizes, int n_in,
                              void* d_out, int out_size, void* d_ws, size_t ws_size,
                              hipStream_t stream) {
    const float* nf   = (const float*)d_in[0];
    const float* ang  = (const float*)d_in[1];
    const int*   eidx = (const int*)d_in[2];
    const float* w    = (const float*)d_in[3];
    float* out = (float*)d_out;

    int n_edges = in_sizes[2] / 2;
    int n_nodes = out_size / OUT_DIM;

    // ws layout (ints): cursor[n_nodes] | spill_cnt[1] | pad->16B | spill int4[SPILL_CAP]
    //                   | buckets int2[n_nodes*cap]
    size_t off_cursor = 0;
    size_t off_spillc = off_cursor + (size_t)n_nodes;
    size_t off_spill  = (off_spillc + 1 + 3) & ~(size_t)3;       // 16B align
    size_t off_buckets = off_spill + 4 * (size_t)SPILL_CAP;      // 16B aligned -> 8B ok

    int cap = 2048;
    while (cap >= 64 &&
           (off_buckets + 2 * (size_t)n_nodes * (size_t)cap) * sizeof(int) > ws_size)
        cap >>= 1;

    if (cap < 64) {
        // ws too small for bucket scheme: atomic path (correct, slower)
        hipMemsetAsync(d_out, 0, (size_t)out_size * sizeof(float), stream);
        int threads_total = n_edges * 8;
        int grid = (threads_total + 255) / 256;
        conv_tp_edges_atomic<<<grid, 256, 0, stream>>>(nf, ang, eidx, w, out, n_edges);
        return;
    }

    int*  cursor    = (int*)d_ws + off_cursor;
    int*  spill_cnt = (int*)d_ws + off_spillc;
    int4* spill     = (int4*)((int*)d_ws + off_spill);
    int2* buckets   = (int2*)((int*)d_ws + off_buckets);

    // zero cursor + spill_cnt (contiguous)
    hipMemsetAsync(cursor, 0, ((size_t)n_nodes + 1) * sizeof(int), stream);

    // cooperative grid sizing: co-resident blocks per CU from the occupancy API
    int maxb = 0;
    hipError_t oe = hipOccupancyMaxActiveBlocksPerMultiprocessor(&maxb, fused_conv, 256, 0);
    if (oe != hipSuccess || maxb < 1) maxb = 2;   // conservative
    if (maxb > 8) maxb = 8;
    int grid = maxb * 256;                        // 256 CUs on MI355X

    void* args[] = {
        (void*)&nf, (void*)&ang, (void*)&eidx, (void*)&w,
        (void*)&cursor, (void*)&spill_cnt, (void*)&spill, (void*)&buckets,
        (void*)&out, (void*)&n_edges, (void*)&n_nodes, (void*)&cap
    };
    hipError_t le = hipLaunchCooperativeKernel((const void*)fused_conv,
                                               dim3(grid), dim3(256),
                                               args, 0, stream);
    if (le != hipSuccess) {
        // non-cooperative fallback: same phases, stream-ordered
        int n_half = (n_edges + 1) / 2;
        int grid_s = (n_half + 255) / 256;
        scatter_k<<<grid_s, 256, 0, stream>>>(eidx, cursor, spill_cnt, spill,
                                              buckets, cap, n_edges);
        int grid_g = ((size_t)n_nodes * 64 + 255) / 256;
        gather_k<<<grid_g, 256, 0, stream>>>(nf, ang, w, cursor, buckets, cap,
                                             out, n_nodes);
        spill_k<<<64, 256, 0, stream>>>(nf, ang, w, spill_cnt, spill, out);
    }
}